// Round 4
// baseline (46.668 us; speedup 1.0000x reference)
//
#include <hip/hip_runtime.h>
#include <math.h>

constexpr int B_DIM = 4096;
constexpr int HO_DIM = 64;
constexpr int NTOT = B_DIM * HO_DIM;
constexpr float SIGMA_R = 0.05f;
constexpr float SIGMA_T = 0.03f;

typedef float f4 __attribute__((ext_vector_type(4)));

// Fast exp of se(3) twist (w=[x,y,z], v=[vx,vy,vz]) -> R (row-major 3x3), t.
__device__ __forceinline__ void exp_se3(float x, float y, float z,
                                        float vx, float vy, float vz,
                                        float R[9], float t[3]) {
    float th2 = x*x + y*y + z*z;
    bool small = th2 < 1e-8f;
    float th2s = small ? 1.0f : th2;
    float th = __builtin_amdgcn_sqrtf(th2s);
    float s = __sinf(th);
    float c = __cosf(th);
    float rth  = __builtin_amdgcn_rcpf(th);
    float rth2 = rth * rth;
    float A  = small ? (1.0f - th2 * (1.0f/6.0f))        : (s * rth);
    float Bc = small ? (0.5f - th2 * (1.0f/24.0f))       : ((1.0f - c) * rth2);
    float Cc = small ? (1.0f/6.0f - th2 * (1.0f/120.0f)) : ((th - s) * rth2 * rth);
    R[0] = 1.0f + Bc*(x*x - th2);
    R[1] = -A*z + Bc*x*y;
    R[2] =  A*y + Bc*x*z;
    R[3] =  A*z + Bc*x*y;
    R[4] = 1.0f + Bc*(y*y - th2);
    R[5] = -A*x + Bc*y*z;
    R[6] = -A*y + Bc*x*z;
    R[7] =  A*x + Bc*y*z;
    R[8] = 1.0f + Bc*(z*z - th2);
    float V0 = 1.0f + Cc*(x*x - th2);
    float V1 = -Bc*z + Cc*x*y;
    float V2 =  Bc*y + Cc*x*z;
    float V3 =  Bc*z + Cc*x*y;
    float V4 = 1.0f + Cc*(y*y - th2);
    float V5 = -Bc*x + Cc*y*z;
    float V6 = -Bc*y + Cc*x*z;
    float V7 =  Bc*x + Cc*y*z;
    float V8 = 1.0f + Cc*(z*z - th2);
    t[0] = V0*vx + V1*vy + V2*vz;
    t[1] = V3*vx + V4*vy + V5*vz;
    t[2] = V6*vx + V7*vy + V8*vz;
}

// One row: twist a[6], noise n[6], per-row scales -> write two 4x4 matrices.
__device__ __forceinline__ void process_row(
    float ax, float ay, float az, float avx, float avy, float avz,
    float nx, float ny, float nz, float nvx, float nvy, float nvz,
    float sab, float kr, float kt,
    float* __restrict__ o0, float* __restrict__ o1)
{
    // H_t = exp(sqrt(ab) * twist)   (log(inv(exp(tw))) = -tw; colinear
    // exponentials compose additively)
    float Rt[9], tt[3];
    exp_se3(sab*ax, sab*ay, sab*az, sab*avx, sab*avy, sab*avz, Rt, tt);

    // H_noise = exp(sqrt(1-ab) * scale * noise)
    float Rn[9], tn[3];
    exp_se3(kr*nx, kr*ny, kr*nz, kt*nvx, kt*nvy, kt*nvz, Rn, tn);

    // out0 = H_noise @ H_t
    float R0[9], t0[3];
    #pragma unroll
    for (int r = 0; r < 3; ++r) {
        #pragma unroll
        for (int cidx = 0; cidx < 3; ++cidx) {
            R0[3*r+cidx] = Rn[3*r+0]*Rt[0+cidx] + Rn[3*r+1]*Rt[3+cidx] + Rn[3*r+2]*Rt[6+cidx];
        }
    }
    t0[0] = Rn[0]*tt[0]+Rn[1]*tt[1]+Rn[2]*tt[2] + tn[0];
    t0[1] = Rn[3]*tt[0]+Rn[4]*tt[1]+Rn[5]*tt[2] + tn[1];
    t0[2] = Rn[6]*tt[0]+Rn[7]*tt[1]+Rn[8]*tt[2] + tn[2];

    __builtin_nontemporal_store((f4){R0[0], R0[1], R0[2], t0[0]}, (f4*)(o0 + 0));
    __builtin_nontemporal_store((f4){R0[3], R0[4], R0[5], t0[1]}, (f4*)(o0 + 4));
    __builtin_nontemporal_store((f4){R0[6], R0[7], R0[8], t0[2]}, (f4*)(o0 + 8));
    __builtin_nontemporal_store((f4){0.0f, 0.0f, 0.0f, 1.0f},    (f4*)(o0 + 12));

    __builtin_nontemporal_store((f4){Rn[0], Rn[1], Rn[2], tn[0]}, (f4*)(o1 + 0));
    __builtin_nontemporal_store((f4){Rn[3], Rn[4], Rn[5], tn[1]}, (f4*)(o1 + 4));
    __builtin_nontemporal_store((f4){Rn[6], Rn[7], Rn[8], tn[2]}, (f4*)(o1 + 8));
    __builtin_nontemporal_store((f4){0.0f, 0.0f, 0.0f, 1.0f},    (f4*)(o1 + 12));
}

__global__ __launch_bounds__(256) void DiffusionScheduler_kernel(
    const float* __restrict__ twist, const float* __restrict__ noise,
    const float* __restrict__ alpha_bars, const int* __restrict__ timesteps,
    float* __restrict__ out)
{
    int j = blockIdx.x * blockDim.x + threadIdx.x;
    if (j >= NTOT / 2) return;
    size_t r = 2 * (size_t)j;

    // Two rows per thread: 48B contiguous -> 3x float4 loads per input.
    const f4* tw = (const f4*)(twist + 6 * r);
    f4 t0 = __builtin_nontemporal_load(tw + 0);
    f4 t1 = __builtin_nontemporal_load(tw + 1);
    f4 t2 = __builtin_nontemporal_load(tw + 2);
    const f4* nq = (const f4*)(noise + 6 * r);
    f4 q0 = __builtin_nontemporal_load(nq + 0);
    f4 q1 = __builtin_nontemporal_load(nq + 1);
    f4 q2 = __builtin_nontemporal_load(nq + 2);

    // rows r and r+1 share b (r even => same i>>6)
    int ts = timesteps[r >> 6];
    float ab = alpha_bars[ts];
    float sab = __builtin_amdgcn_sqrtf(ab);
    float sq  = __builtin_amdgcn_sqrtf(1.0f - ab);
    float kr = sq * SIGMA_R, kt = sq * SIGMA_T;

    float* o0 = out + 16 * r;
    float* o1 = out + (size_t)NTOT * 16 + 16 * r;

    process_row(t0.x, t0.y, t0.z, t0.w, t1.x, t1.y,
                q0.x, q0.y, q0.z, q0.w, q1.x, q1.y,
                sab, kr, kt, o0, o1);
    process_row(t1.z, t1.w, t2.x, t2.y, t2.z, t2.w,
                q1.z, q1.w, q2.x, q2.y, q2.z, q2.w,
                sab, kr, kt, o0 + 16, o1 + 16);
}

extern "C" void kernel_launch(void* const* d_in, const int* in_sizes, int n_in,
                              void* d_out, int out_size, void* d_ws, size_t ws_size,
                              hipStream_t stream) {
    const float* twist       = (const float*)d_in[0];
    const float* noise       = (const float*)d_in[1];
    const float* alpha_bars  = (const float*)d_in[2];
    const int*   timesteps   = (const int*)d_in[3];
    float* out = (float*)d_out;

    dim3 block(256);
    dim3 grid((NTOT / 2 + 255) / 256);
    hipLaunchKernelGGL(DiffusionScheduler_kernel, grid, block, 0, stream,
                       twist, noise, alpha_bars, timesteps, out);
}

// Round 5
// 21.618 us; speedup vs baseline: 2.1588x; 2.1588x over previous
//
#include <hip/hip_runtime.h>
#include <math.h>

constexpr int B_DIM = 4096;
constexpr int HO_DIM = 64;
constexpr int NTOT = B_DIM * HO_DIM;
constexpr int NBLK_HALF = NTOT / 256;     // 1024 blocks per output half
constexpr float SIGMA_R = 0.05f;
constexpr float SIGMA_T = 0.03f;

typedef float f4 __attribute__((ext_vector_type(4)));
typedef float f2 __attribute__((ext_vector_type(2)));

// Fast exp of se(3) twist (w=[x,y,z], v=[vx,vy,vz]) -> R (row-major 3x3), t.
__device__ __forceinline__ void exp_se3(float x, float y, float z,
                                        float vx, float vy, float vz,
                                        float R[9], float t[3]) {
    float th2 = x*x + y*y + z*z;
    bool small = th2 < 1e-8f;
    float th2s = small ? 1.0f : th2;
    float th = __builtin_amdgcn_sqrtf(th2s);
    float s = __sinf(th);
    float c = __cosf(th);
    float rth  = __builtin_amdgcn_rcpf(th);
    float rth2 = rth * rth;
    float A  = small ? (1.0f - th2 * (1.0f/6.0f))        : (s * rth);
    float Bc = small ? (0.5f - th2 * (1.0f/24.0f))       : ((1.0f - c) * rth2);
    float Cc = small ? (1.0f/6.0f - th2 * (1.0f/120.0f)) : ((th - s) * rth2 * rth);
    R[0] = 1.0f + Bc*(x*x - th2);
    R[1] = -A*z + Bc*x*y;
    R[2] =  A*y + Bc*x*z;
    R[3] =  A*z + Bc*x*y;
    R[4] = 1.0f + Bc*(y*y - th2);
    R[5] = -A*x + Bc*y*z;
    R[6] = -A*y + Bc*x*z;
    R[7] =  A*x + Bc*y*z;
    R[8] = 1.0f + Bc*(z*z - th2);
    float V0 = 1.0f + Cc*(x*x - th2);
    float V1 = -Bc*z + Cc*x*y;
    float V2 =  Bc*y + Cc*x*z;
    float V3 =  Bc*z + Cc*x*y;
    float V4 = 1.0f + Cc*(y*y - th2);
    float V5 = -Bc*x + Cc*y*z;
    float V6 = -Bc*y + Cc*x*z;
    float V7 =  Bc*x + Cc*y*z;
    float V8 = 1.0f + Cc*(z*z - th2);
    t[0] = V0*vx + V1*vy + V2*vz;
    t[1] = V3*vx + V4*vy + V5*vz;
    t[2] = V6*vx + V7*vy + V8*vz;
}

__global__ __launch_bounds__(256) void DiffusionScheduler_kernel(
    const float* __restrict__ twist, const float* __restrict__ noise,
    const float* __restrict__ alpha_bars, const int* __restrict__ timesteps,
    float* __restrict__ out)
{
    int b = blockIdx.x;
    bool second = (b >= NBLK_HALF);           // block-uniform branch
    int rb = second ? b - NBLK_HALF : b;
    size_t r = (size_t)rb * 256 + threadIdx.x;

    int ts = timesteps[r >> 6];
    float ab = alpha_bars[ts];
    float sq = __builtin_amdgcn_sqrtf(1.0f - ab);
    float kr = sq * SIGMA_R, kt = sq * SIGMA_T;

    // noise row (both halves need it)
    const f2* nz = (const f2*)(noise + 6 * r);
    f2 n0 = __builtin_nontemporal_load(nz + 0);
    f2 n1 = __builtin_nontemporal_load(nz + 1);
    f2 n2 = __builtin_nontemporal_load(nz + 2);

    // H_noise = exp(sqrt(1-ab) * scale * noise)
    float Rn[9], tn[3];
    exp_se3(kr*n0.x, kr*n0.y, kr*n1.x, kt*n1.y, kt*n2.x, kt*n2.y, Rn, tn);

    if (second) {
        // out1 = H_noise
        f4* o1 = (f4*)(out + (size_t)NTOT * 16 + 16 * r);
        o1[0] = (f4){Rn[0], Rn[1], Rn[2], tn[0]};
        o1[1] = (f4){Rn[3], Rn[4], Rn[5], tn[1]};
        o1[2] = (f4){Rn[6], Rn[7], Rn[8], tn[2]};
        o1[3] = (f4){0.0f, 0.0f, 0.0f, 1.0f};
        return;
    }

    // first half: out0 = H_noise @ H_t,  H_t = exp(sqrt(ab)*twist)
    const f2* tw = (const f2*)(twist + 6 * r);
    f2 a0 = __builtin_nontemporal_load(tw + 0);
    f2 a1 = __builtin_nontemporal_load(tw + 1);
    f2 a2 = __builtin_nontemporal_load(tw + 2);

    float sab = __builtin_amdgcn_sqrtf(ab);
    float Rt[9], tt[3];
    exp_se3(sab*a0.x, sab*a0.y, sab*a1.x, sab*a1.y, sab*a2.x, sab*a2.y, Rt, tt);

    float R0[9], t0v[3];
    #pragma unroll
    for (int rr = 0; rr < 3; ++rr) {
        #pragma unroll
        for (int cc = 0; cc < 3; ++cc) {
            R0[3*rr+cc] = Rn[3*rr+0]*Rt[0+cc] + Rn[3*rr+1]*Rt[3+cc] + Rn[3*rr+2]*Rt[6+cc];
        }
    }
    t0v[0] = Rn[0]*tt[0]+Rn[1]*tt[1]+Rn[2]*tt[2] + tn[0];
    t0v[1] = Rn[3]*tt[0]+Rn[4]*tt[1]+Rn[5]*tt[2] + tn[1];
    t0v[2] = Rn[6]*tt[0]+Rn[7]*tt[1]+Rn[8]*tt[2] + tn[2];

    f4* o0 = (f4*)(out + 16 * r);
    o0[0] = (f4){R0[0], R0[1], R0[2], t0v[0]};
    o0[1] = (f4){R0[3], R0[4], R0[5], t0v[1]};
    o0[2] = (f4){R0[6], R0[7], R0[8], t0v[2]};
    o0[3] = (f4){0.0f, 0.0f, 0.0f, 1.0f};
}

extern "C" void kernel_launch(void* const* d_in, const int* in_sizes, int n_in,
                              void* d_out, int out_size, void* d_ws, size_t ws_size,
                              hipStream_t stream) {
    const float* twist       = (const float*)d_in[0];
    const float* noise       = (const float*)d_in[1];
    const float* alpha_bars  = (const float*)d_in[2];
    const int*   timesteps   = (const int*)d_in[3];
    float* out = (float*)d_out;

    dim3 block(256);
    dim3 grid(2 * NBLK_HALF);
    hipLaunchKernelGGL(DiffusionScheduler_kernel, grid, block, 0, stream,
                       twist, noise, alpha_bars, timesteps, out);
}

// Round 6
// 16.733 us; speedup vs baseline: 2.7890x; 1.2919x over previous
//
#include <hip/hip_runtime.h>
#include <math.h>

constexpr int B_DIM = 4096;
constexpr int HO_DIM = 64;
constexpr int NTOT = B_DIM * HO_DIM;      // 262144 rows
constexpr int QTOT = NTOT * 4;            // one thread per output matrix ROW
constexpr int NBLK = QTOT / 256;          // 4096 blocks per output half
constexpr float SIGMA_R = 0.05f;
constexpr float SIGMA_T = 0.03f;

typedef float f4 __attribute__((ext_vector_type(4)));
typedef float f2 __attribute__((ext_vector_type(2)));

// Fast exp of se(3) twist (w=[x,y,z], v=[vx,vy,vz]) -> R (row-major 3x3), t.
__device__ __forceinline__ void exp_se3(float x, float y, float z,
                                        float vx, float vy, float vz,
                                        float R[9], float t[3]) {
    float th2 = x*x + y*y + z*z;
    bool small = th2 < 1e-8f;
    float th2s = small ? 1.0f : th2;
    float th = __builtin_amdgcn_sqrtf(th2s);
    float s = __sinf(th);
    float c = __cosf(th);
    float rth  = __builtin_amdgcn_rcpf(th);
    float rth2 = rth * rth;
    float A  = small ? (1.0f - th2 * (1.0f/6.0f))        : (s * rth);
    float Bc = small ? (0.5f - th2 * (1.0f/24.0f))       : ((1.0f - c) * rth2);
    float Cc = small ? (1.0f/6.0f - th2 * (1.0f/120.0f)) : ((th - s) * rth2 * rth);
    R[0] = 1.0f + Bc*(x*x - th2);
    R[1] = -A*z + Bc*x*y;
    R[2] =  A*y + Bc*x*z;
    R[3] =  A*z + Bc*x*y;
    R[4] = 1.0f + Bc*(y*y - th2);
    R[5] = -A*x + Bc*y*z;
    R[6] = -A*y + Bc*x*z;
    R[7] =  A*x + Bc*y*z;
    R[8] = 1.0f + Bc*(z*z - th2);
    float V0 = 1.0f + Cc*(x*x - th2);
    float V1 = -Bc*z + Cc*x*y;
    float V2 =  Bc*y + Cc*x*z;
    float V3 =  Bc*z + Cc*x*y;
    float V4 = 1.0f + Cc*(y*y - th2);
    float V5 = -Bc*x + Cc*y*z;
    float V6 = -Bc*y + Cc*x*z;
    float V7 =  Bc*x + Cc*y*z;
    float V8 = 1.0f + Cc*(z*z - th2);
    t[0] = V0*vx + V1*vy + V2*vz;
    t[1] = V3*vx + V4*vy + V5*vz;
    t[2] = V6*vx + V7*vy + V8*vz;
}

__global__ __launch_bounds__(256) void DiffusionScheduler_kernel(
    const float* __restrict__ twist, const float* __restrict__ noise,
    const float* __restrict__ alpha_bars, const int* __restrict__ timesteps,
    float* __restrict__ out)
{
    int b = blockIdx.x;
    bool second = (b >= NBLK);                 // block-uniform branch
    int bb = second ? b - NBLK : b;
    int k = bb * 256 + threadIdx.x;            // output-row index within half
    int mat = k >> 2;                          // which (b,ho) row
    int rr  = k & 3;                           // which matrix row 0..3

    // mat>>6 == bb exactly (64 matrices per block) -> scalar load
    int ts = timesteps[bb];
    float ab = alpha_bars[ts];
    float sq = __builtin_amdgcn_sqrtf(1.0f - ab);
    float kr = sq * SIGMA_R, kt = sq * SIGMA_T;

    // noise row (needed by both halves); 4 lanes/group share -> L1 broadcast
    const f2* nz = (const f2*)(noise + 6 * (size_t)mat);
    f2 n0 = nz[0], n1 = nz[1], n2 = nz[2];

    // H_noise = exp(sqrt(1-ab) * scale * noise)
    float Rn[9], tn[3];
    exp_se3(kr*n0.x, kr*n0.y, kr*n1.x, kt*n1.y, kt*n2.x, kt*n2.y, Rn, tn);

    // select row rr of [Rn | tn]  (compile-time indices only -> cndmask, no scratch)
    float q0 = rr==0 ? Rn[0] : (rr==1 ? Rn[3] : Rn[6]);
    float q1 = rr==0 ? Rn[1] : (rr==1 ? Rn[4] : Rn[7]);
    float q2 = rr==0 ? Rn[2] : (rr==1 ? Rn[5] : Rn[8]);
    float qt = rr==0 ? tn[0] : (rr==1 ? tn[1] : tn[2]);

    f4 row;
    if (second) {
        // out1 row = [Rn_rr | tn_rr]
        row = (rr == 3) ? (f4){0.0f, 0.0f, 0.0f, 1.0f} : (f4){q0, q1, q2, qt};
        f4* o1 = (f4*)(out + (size_t)NTOT * 16);
        o1[k] = row;                           // lane-contiguous dwordx4
        return;
    }

    // first half: out0 = H_noise @ H_t, H_t = exp(sqrt(ab)*twist)
    // (log(inv(exp(tw))) = -tw; colinear exponentials compose additively)
    const f2* tw = (const f2*)(twist + 6 * (size_t)mat);
    f2 a0 = tw[0], a1 = tw[1], a2 = tw[2];
    float sab = __builtin_amdgcn_sqrtf(ab);
    float Rt[9], tt[3];
    exp_se3(sab*a0.x, sab*a0.y, sab*a1.x, sab*a1.y, sab*a2.x, sab*a2.y, Rt, tt);

    float r0 = q0*Rt[0] + q1*Rt[3] + q2*Rt[6];
    float r1 = q0*Rt[1] + q1*Rt[4] + q2*Rt[7];
    float r2 = q0*Rt[2] + q1*Rt[5] + q2*Rt[8];
    float r3 = q0*tt[0] + q1*tt[1] + q2*tt[2] + qt;
    row = (rr == 3) ? (f4){0.0f, 0.0f, 0.0f, 1.0f} : (f4){r0, r1, r2, r3};
    ((f4*)out)[k] = row;                       // lane-contiguous dwordx4
}

extern "C" void kernel_launch(void* const* d_in, const int* in_sizes, int n_in,
                              void* d_out, int out_size, void* d_ws, size_t ws_size,
                              hipStream_t stream) {
    const float* twist       = (const float*)d_in[0];
    const float* noise       = (const float*)d_in[1];
    const float* alpha_bars  = (const float*)d_in[2];
    const int*   timesteps   = (const int*)d_in[3];
    float* out = (float*)d_out;

    dim3 block(256);
    dim3 grid(2 * NBLK);
    hipLaunchKernelGGL(DiffusionScheduler_kernel, grid, block, 0, stream,
                       twist, noise, alpha_bars, timesteps, out);
}

// Round 7
// 15.022 us; speedup vs baseline: 3.1067x; 1.1139x over previous
//
#include <hip/hip_runtime.h>
#include <math.h>

constexpr int B_DIM = 4096;
constexpr int HO_DIM = 64;
constexpr int NTOT = B_DIM * HO_DIM;      // 262144 matrices per output
constexpr int QTOT = NTOT * 4;            // one thread per output matrix ROW
constexpr int NBLK = QTOT / 256;          // 4096 blocks (== B_DIM)
constexpr float SIGMA_R = 0.05f;
constexpr float SIGMA_T = 0.03f;

typedef float f4 __attribute__((ext_vector_type(4)));
typedef float f2 __attribute__((ext_vector_type(2)));

// Fast exp of se(3) twist (w=[x,y,z], v=[vx,vy,vz]) -> R (row-major 3x3), t.
__device__ __forceinline__ void exp_se3(float x, float y, float z,
                                        float vx, float vy, float vz,
                                        float R[9], float t[3]) {
    float th2 = x*x + y*y + z*z;
    bool small = th2 < 1e-8f;
    float th2s = small ? 1.0f : th2;
    float th = __builtin_amdgcn_sqrtf(th2s);
    float s = __sinf(th);
    float c = __cosf(th);
    float rth  = __builtin_amdgcn_rcpf(th);
    float rth2 = rth * rth;
    float A  = small ? (1.0f - th2 * (1.0f/6.0f))        : (s * rth);
    float Bc = small ? (0.5f - th2 * (1.0f/24.0f))       : ((1.0f - c) * rth2);
    float Cc = small ? (1.0f/6.0f - th2 * (1.0f/120.0f)) : ((th - s) * rth2 * rth);
    R[0] = 1.0f + Bc*(x*x - th2);
    R[1] = -A*z + Bc*x*y;
    R[2] =  A*y + Bc*x*z;
    R[3] =  A*z + Bc*x*y;
    R[4] = 1.0f + Bc*(y*y - th2);
    R[5] = -A*x + Bc*y*z;
    R[6] = -A*y + Bc*x*z;
    R[7] =  A*x + Bc*y*z;
    R[8] = 1.0f + Bc*(z*z - th2);
    float V0 = 1.0f + Cc*(x*x - th2);
    float V1 = -Bc*z + Cc*x*y;
    float V2 =  Bc*y + Cc*x*z;
    float V3 =  Bc*z + Cc*x*y;
    float V4 = 1.0f + Cc*(y*y - th2);
    float V5 = -Bc*x + Cc*y*z;
    float V6 = -Bc*y + Cc*x*z;
    float V7 =  Bc*x + Cc*y*z;
    float V8 = 1.0f + Cc*(z*z - th2);
    t[0] = V0*vx + V1*vy + V2*vz;
    t[1] = V3*vx + V4*vy + V5*vz;
    t[2] = V6*vx + V7*vy + V8*vz;
}

__global__ __launch_bounds__(256) void DiffusionScheduler_kernel(
    const float* __restrict__ twist, const float* __restrict__ noise,
    const float* __restrict__ alpha_bars, const int* __restrict__ timesteps,
    float* __restrict__ out)
{
    int k = blockIdx.x * 256 + threadIdx.x;    // output row index 0..QTOT
    int mat = k >> 2;                          // which (b,ho) matrix
    int rr  = k & 3;                           // which matrix row 0..3

    // 64 matrices per block == exactly one batch element -> scalar loads
    int ts = timesteps[blockIdx.x];
    float ab = alpha_bars[ts];
    float sab = __builtin_amdgcn_sqrtf(ab);
    float sq  = __builtin_amdgcn_sqrtf(1.0f - ab);
    float kr = sq * SIGMA_R, kt = sq * SIGMA_T;

    // loads: 4 lanes/group share a matrix -> L1 broadcast, L3-resident
    const f2* nz = (const f2*)(noise + 6 * (size_t)mat);
    f2 n0 = nz[0], n1 = nz[1], n2 = nz[2];
    const f2* tw = (const f2*)(twist + 6 * (size_t)mat);
    f2 a0 = tw[0], a1 = tw[1], a2 = tw[2];

    // H_noise = exp(sqrt(1-ab) * scale * noise)
    float Rn[9], tn[3];
    exp_se3(kr*n0.x, kr*n0.y, kr*n1.x, kt*n1.y, kt*n2.x, kt*n2.y, Rn, tn);

    // H_t = exp(sqrt(ab)*twist)
    // (log(inv(exp(tw))) = -tw; colinear exponentials compose additively)
    float Rt[9], tt[3];
    exp_se3(sab*a0.x, sab*a0.y, sab*a1.x, sab*a1.y, sab*a2.x, sab*a2.y, Rt, tt);

    // row rr of [Rn | tn] (compile-time indices -> cndmask, no scratch)
    float q0 = rr==0 ? Rn[0] : (rr==1 ? Rn[3] : Rn[6]);
    float q1 = rr==0 ? Rn[1] : (rr==1 ? Rn[4] : Rn[7]);
    float q2 = rr==0 ? Rn[2] : (rr==1 ? Rn[5] : Rn[8]);
    float qt = rr==0 ? tn[0] : (rr==1 ? tn[1] : tn[2]);

    // out0 row = row rr of [Rn@Rt | Rn@tt + tn]
    float r0 = q0*Rt[0] + q1*Rt[3] + q2*Rt[6];
    float r1 = q0*Rt[1] + q1*Rt[4] + q2*Rt[7];
    float r2 = q0*Rt[2] + q1*Rt[5] + q2*Rt[8];
    float r3 = q0*tt[0] + q1*tt[1] + q2*tt[2] + qt;

    f4 row0 = (rr == 3) ? (f4){0.0f, 0.0f, 0.0f, 1.0f} : (f4){r0, r1, r2, r3};
    f4 row1 = (rr == 3) ? (f4){0.0f, 0.0f, 0.0f, 1.0f} : (f4){q0, q1, q2, qt};

    ((f4*)out)[k] = row0;                               // lane-contiguous
    ((f4*)(out + (size_t)NTOT * 16))[k] = row1;         // lane-contiguous
}

extern "C" void kernel_launch(void* const* d_in, const int* in_sizes, int n_in,
                              void* d_out, int out_size, void* d_ws, size_t ws_size,
                              hipStream_t stream) {
    const float* twist       = (const float*)d_in[0];
    const float* noise       = (const float*)d_in[1];
    const float* alpha_bars  = (const float*)d_in[2];
    const int*   timesteps   = (const int*)d_in[3];
    float* out = (float*)d_out;

    dim3 block(256);
    dim3 grid(NBLK);
    hipLaunchKernelGGL(DiffusionScheduler_kernel, grid, block, 0, stream,
                       twist, noise, alpha_bars, timesteps, out);
}

// Round 8
// 13.812 us; speedup vs baseline: 3.3787x; 1.0875x over previous
//
#include <hip/hip_runtime.h>
#include <math.h>

constexpr int B_DIM = 4096;
constexpr int HO_DIM = 64;
constexpr int NTOT = B_DIM * HO_DIM;      // 262144 matrices per output
constexpr int MPB  = 256;                 // matrices per block (= threads)
constexpr int NBLK = NTOT / MPB;          // 1024 blocks
constexpr float SIGMA_R = 0.05f;
constexpr float SIGMA_T = 0.03f;

typedef float f4 __attribute__((ext_vector_type(4)));
typedef float f2 __attribute__((ext_vector_type(2)));

// Fast exp of se(3) twist (w=[x,y,z], v=[vx,vy,vz]) -> R (row-major 3x3), t.
__device__ __forceinline__ void exp_se3(float x, float y, float z,
                                        float vx, float vy, float vz,
                                        float R[9], float t[3]) {
    float th2 = x*x + y*y + z*z;
    bool small = th2 < 1e-8f;
    float th2s = small ? 1.0f : th2;
    float th = __builtin_amdgcn_sqrtf(th2s);
    float s = __sinf(th);
    float c = __cosf(th);
    float rth  = __builtin_amdgcn_rcpf(th);
    float rth2 = rth * rth;
    float A  = small ? (1.0f - th2 * (1.0f/6.0f))        : (s * rth);
    float Bc = small ? (0.5f - th2 * (1.0f/24.0f))       : ((1.0f - c) * rth2);
    float Cc = small ? (1.0f/6.0f - th2 * (1.0f/120.0f)) : ((th - s) * rth2 * rth);
    R[0] = 1.0f + Bc*(x*x - th2);
    R[1] = -A*z + Bc*x*y;
    R[2] =  A*y + Bc*x*z;
    R[3] =  A*z + Bc*x*y;
    R[4] = 1.0f + Bc*(y*y - th2);
    R[5] = -A*x + Bc*y*z;
    R[6] = -A*y + Bc*x*z;
    R[7] =  A*x + Bc*y*z;
    R[8] = 1.0f + Bc*(z*z - th2);
    float V0 = 1.0f + Cc*(x*x - th2);
    float V1 = -Bc*z + Cc*x*y;
    float V2 =  Bc*y + Cc*x*z;
    float V3 =  Bc*z + Cc*x*y;
    float V4 = 1.0f + Cc*(y*y - th2);
    float V5 = -Bc*x + Cc*y*z;
    float V6 = -Bc*y + Cc*x*z;
    float V7 =  Bc*x + Cc*y*z;
    float V8 = 1.0f + Cc*(z*z - th2);
    t[0] = V0*vx + V1*vy + V2*vz;
    t[1] = V3*vx + V4*vy + V5*vz;
    t[2] = V6*vx + V7*vy + V8*vz;
}

__global__ __launch_bounds__(256) void DiffusionScheduler_kernel(
    const float* __restrict__ twist, const float* __restrict__ noise,
    const float* __restrict__ alpha_bars, const int* __restrict__ timesteps,
    float* __restrict__ out)
{
    // [elem][mat] transposed staging; stride 258 -> all LDS ops <=2-way (free)
    __shared__ float lds0[16][258];
    __shared__ float lds1[16][258];

    int t = threadIdx.x;
    size_t mat = (size_t)blockIdx.x * MPB + t;

    int ts = timesteps[mat >> 6];
    float ab = alpha_bars[ts];
    float sab = __builtin_amdgcn_sqrtf(ab);
    float sq  = __builtin_amdgcn_sqrtf(1.0f - ab);
    float kr = sq * SIGMA_R, kt = sq * SIGMA_T;

    // each matrix's inputs loaded exactly once
    const f2* nz = (const f2*)(noise + 6 * mat);
    f2 n0 = nz[0], n1 = nz[1], n2 = nz[2];
    const f2* tw = (const f2*)(twist + 6 * mat);
    f2 a0 = tw[0], a1 = tw[1], a2 = tw[2];

    // H_noise = exp(sqrt(1-ab) * scale * noise)
    float Rn[9], tn[3];
    exp_se3(kr*n0.x, kr*n0.y, kr*n1.x, kt*n1.y, kt*n2.x, kt*n2.y, Rn, tn);

    // H_t = exp(sqrt(ab)*twist)
    // (log(inv(exp(tw))) = -tw; colinear exponentials compose additively)
    float Rt[9], tt[3];
    exp_se3(sab*a0.x, sab*a0.y, sab*a1.x, sab*a1.y, sab*a2.x, sab*a2.y, Rt, tt);

    // out0 = H_noise @ H_t (full product, computed once)
    float R0[9], t0[3];
    #pragma unroll
    for (int r = 0; r < 3; ++r) {
        #pragma unroll
        for (int cdx = 0; cdx < 3; ++cdx) {
            R0[3*r+cdx] = Rn[3*r+0]*Rt[0+cdx] + Rn[3*r+1]*Rt[3+cdx] + Rn[3*r+2]*Rt[6+cdx];
        }
    }
    t0[0] = Rn[0]*tt[0]+Rn[1]*tt[1]+Rn[2]*tt[2] + tn[0];
    t0[1] = Rn[3]*tt[0]+Rn[4]*tt[1]+Rn[5]*tt[2] + tn[1];
    t0[2] = Rn[6]*tt[0]+Rn[7]*tt[1]+Rn[8]*tt[2] + tn[2];

    // stage row-major 4x4 into [elem][mat]
    lds0[ 0][t] = R0[0]; lds0[ 1][t] = R0[1]; lds0[ 2][t] = R0[2]; lds0[ 3][t] = t0[0];
    lds0[ 4][t] = R0[3]; lds0[ 5][t] = R0[4]; lds0[ 6][t] = R0[5]; lds0[ 7][t] = t0[1];
    lds0[ 8][t] = R0[6]; lds0[ 9][t] = R0[7]; lds0[10][t] = R0[8]; lds0[11][t] = t0[2];
    lds0[12][t] = 0.0f;  lds0[13][t] = 0.0f;  lds0[14][t] = 0.0f;  lds0[15][t] = 1.0f;

    lds1[ 0][t] = Rn[0]; lds1[ 1][t] = Rn[1]; lds1[ 2][t] = Rn[2]; lds1[ 3][t] = tn[0];
    lds1[ 4][t] = Rn[3]; lds1[ 5][t] = Rn[4]; lds1[ 6][t] = Rn[5]; lds1[ 7][t] = tn[1];
    lds1[ 8][t] = Rn[6]; lds1[ 9][t] = Rn[7]; lds1[10][t] = Rn[8]; lds1[11][t] = tn[2];
    lds1[12][t] = 0.0f;  lds1[13][t] = 0.0f;  lds1[14][t] = 0.0f;  lds1[15][t] = 1.0f;

    __syncthreads();

    // drain: lane-contiguous dwordx4 stores (the R6 winning pattern)
    int rr = t & 3;            // matrix row this thread stores
    int mb = t >> 2;           // base matrix within chunk
    f4* o0 = ((f4*)out) + (size_t)blockIdx.x * (MPB * 4);
    f4* o1 = o0 + (size_t)NTOT * 4;

    #pragma unroll
    for (int c = 0; c < 4; ++c) {
        int m = c * 64 + mb;
        f4 v = {lds0[4*rr+0][m], lds0[4*rr+1][m], lds0[4*rr+2][m], lds0[4*rr+3][m]};
        o0[c * 256 + t] = v;
    }
    #pragma unroll
    for (int c = 0; c < 4; ++c) {
        int m = c * 64 + mb;
        f4 v = {lds1[4*rr+0][m], lds1[4*rr+1][m], lds1[4*rr+2][m], lds1[4*rr+3][m]};
        o1[c * 256 + t] = v;
    }
}

extern "C" void kernel_launch(void* const* d_in, const int* in_sizes, int n_in,
                              void* d_out, int out_size, void* d_ws, size_t ws_size,
                              hipStream_t stream) {
    const float* twist       = (const float*)d_in[0];
    const float* noise       = (const float*)d_in[1];
    const float* alpha_bars  = (const float*)d_in[2];
    const int*   timesteps   = (const int*)d_in[3];
    float* out = (float*)d_out;

    dim3 block(256);
    dim3 grid(NBLK);
    hipLaunchKernelGGL(DiffusionScheduler_kernel, grid, block, 0, stream,
                       twist, noise, alpha_bars, timesteps, out);
}

// Round 9
// 13.794 us; speedup vs baseline: 3.3832x; 1.0013x over previous
//
#include <hip/hip_runtime.h>
#include <math.h>

constexpr int B_DIM = 4096;
constexpr int HO_DIM = 64;
constexpr int NTOT = B_DIM * HO_DIM;      // 262144 matrices per output
constexpr int MPB  = 256;                 // matrices per block (= threads)
constexpr int NBLK = NTOT / MPB;          // 1024 blocks
constexpr float SIGMA_R = 0.05f;
constexpr float SIGMA_T = 0.03f;

typedef float f4 __attribute__((ext_vector_type(4)));
typedef float f2 __attribute__((ext_vector_type(2)));

// Fast exp of se(3) twist (w=[x,y,z], v=[vx,vy,vz]) -> R (row-major 3x3), t.
__device__ __forceinline__ void exp_se3(float x, float y, float z,
                                        float vx, float vy, float vz,
                                        float R[9], float t[3]) {
    float th2 = x*x + y*y + z*z;
    bool small = th2 < 1e-8f;
    float th2s = small ? 1.0f : th2;
    float th = __builtin_amdgcn_sqrtf(th2s);
    float s = __sinf(th);
    float c = __cosf(th);
    float rth  = __builtin_amdgcn_rcpf(th);
    float rth2 = rth * rth;
    float A  = small ? (1.0f - th2 * (1.0f/6.0f))        : (s * rth);
    float Bc = small ? (0.5f - th2 * (1.0f/24.0f))       : ((1.0f - c) * rth2);
    float Cc = small ? (1.0f/6.0f - th2 * (1.0f/120.0f)) : ((th - s) * rth2 * rth);
    R[0] = 1.0f + Bc*(x*x - th2);
    R[1] = -A*z + Bc*x*y;
    R[2] =  A*y + Bc*x*z;
    R[3] =  A*z + Bc*x*y;
    R[4] = 1.0f + Bc*(y*y - th2);
    R[5] = -A*x + Bc*y*z;
    R[6] = -A*y + Bc*x*z;
    R[7] =  A*x + Bc*y*z;
    R[8] = 1.0f + Bc*(z*z - th2);
    float V0 = 1.0f + Cc*(x*x - th2);
    float V1 = -Bc*z + Cc*x*y;
    float V2 =  Bc*y + Cc*x*z;
    float V3 =  Bc*z + Cc*x*y;
    float V4 = 1.0f + Cc*(y*y - th2);
    float V5 = -Bc*x + Cc*y*z;
    float V6 = -Bc*y + Cc*x*z;
    float V7 =  Bc*x + Cc*y*z;
    float V8 = 1.0f + Cc*(z*z - th2);
    t[0] = V0*vx + V1*vy + V2*vz;
    t[1] = V3*vx + V4*vy + V5*vz;
    t[2] = V6*vx + V7*vy + V8*vz;
}

__global__ __launch_bounds__(256) void DiffusionScheduler_kernel(
    const float* __restrict__ twist, const float* __restrict__ noise,
    const float* __restrict__ alpha_bars, const int* __restrict__ timesteps,
    float* __restrict__ out)
{
    // single [elem][mat] buffer, 12 rows (constant row emitted directly).
    // stride 258 -> all LDS ops <=2-way bank aliasing (free per m136).
    __shared__ float lds[12][258];

    int t = threadIdx.x;
    size_t mat = (size_t)blockIdx.x * MPB + t;

    int ts = timesteps[mat >> 6];              // wave-uniform
    float ab = alpha_bars[ts];
    float sab = __builtin_amdgcn_sqrtf(ab);
    float sq  = __builtin_amdgcn_sqrtf(1.0f - ab);
    float kr = sq * SIGMA_R, kt = sq * SIGMA_T;

    // issue both input loads up front (L3-resident; latency hidden by compute)
    const f2* nz = (const f2*)(noise + 6 * mat);
    f2 n0 = nz[0], n1 = nz[1], n2 = nz[2];
    const f2* tw = (const f2*)(twist + 6 * mat);
    f2 a0 = tw[0], a1 = tw[1], a2 = tw[2];

    // ---- phase A: H_noise = exp(sqrt(1-ab) * scale * noise) ----
    float Rn[9], tn[3];
    exp_se3(kr*n0.x, kr*n0.y, kr*n1.x, kt*n1.y, kt*n2.x, kt*n2.y, Rn, tn);

    lds[ 0][t] = Rn[0]; lds[ 1][t] = Rn[1]; lds[ 2][t] = Rn[2]; lds[ 3][t] = tn[0];
    lds[ 4][t] = Rn[3]; lds[ 5][t] = Rn[4]; lds[ 6][t] = Rn[5]; lds[ 7][t] = tn[1];
    lds[ 8][t] = Rn[6]; lds[ 9][t] = Rn[7]; lds[10][t] = Rn[8]; lds[11][t] = tn[2];

    __syncthreads();

    // drain out1 NOW (stores are fire-and-forget; phase-B VALU hides under them)
    int rr = t & 3;            // matrix row this thread stores
    int mb = t >> 2;           // base matrix within chunk
    f4* o0 = ((f4*)out) + (size_t)blockIdx.x * (MPB * 4);
    f4* o1 = o0 + (size_t)NTOT * 4;

    #pragma unroll
    for (int c = 0; c < 4; ++c) {
        int m = c * 64 + mb;
        f4 v = (rr == 3) ? (f4){0.0f, 0.0f, 0.0f, 1.0f}
                         : (f4){lds[4*rr+0][m], lds[4*rr+1][m], lds[4*rr+2][m], lds[4*rr+3][m]};
        o1[c * 256 + t] = v;                   // lane-contiguous dwordx4
    }

    // ---- phase B (overlaps out1 store drain): H_t and the product ----
    // H_t = exp(sqrt(ab)*twist)
    // (log(inv(exp(tw))) = -tw; colinear exponentials compose additively)
    float Rt[9], tt[3];
    exp_se3(sab*a0.x, sab*a0.y, sab*a1.x, sab*a1.y, sab*a2.x, sab*a2.y, Rt, tt);

    float R0[9], t0[3];
    #pragma unroll
    for (int r = 0; r < 3; ++r) {
        #pragma unroll
        for (int cdx = 0; cdx < 3; ++cdx) {
            R0[3*r+cdx] = Rn[3*r+0]*Rt[0+cdx] + Rn[3*r+1]*Rt[3+cdx] + Rn[3*r+2]*Rt[6+cdx];
        }
    }
    t0[0] = Rn[0]*tt[0]+Rn[1]*tt[1]+Rn[2]*tt[2] + tn[0];
    t0[1] = Rn[3]*tt[0]+Rn[4]*tt[1]+Rn[5]*tt[2] + tn[1];
    t0[2] = Rn[6]*tt[0]+Rn[7]*tt[1]+Rn[8]*tt[2] + tn[2];

    __syncthreads();                           // WAR: all lds reads above done

    lds[ 0][t] = R0[0]; lds[ 1][t] = R0[1]; lds[ 2][t] = R0[2]; lds[ 3][t] = t0[0];
    lds[ 4][t] = R0[3]; lds[ 5][t] = R0[4]; lds[ 6][t] = R0[5]; lds[ 7][t] = t0[1];
    lds[ 8][t] = R0[6]; lds[ 9][t] = R0[7]; lds[10][t] = R0[8]; lds[11][t] = t0[2];

    __syncthreads();

    #pragma unroll
    for (int c = 0; c < 4; ++c) {
        int m = c * 64 + mb;
        f4 v = (rr == 3) ? (f4){0.0f, 0.0f, 0.0f, 1.0f}
                         : (f4){lds[4*rr+0][m], lds[4*rr+1][m], lds[4*rr+2][m], lds[4*rr+3][m]};
        o0[c * 256 + t] = v;                   // lane-contiguous dwordx4
    }
}

extern "C" void kernel_launch(void* const* d_in, const int* in_sizes, int n_in,
                              void* d_out, int out_size, void* d_ws, size_t ws_size,
                              hipStream_t stream) {
    const float* twist       = (const float*)d_in[0];
    const float* noise       = (const float*)d_in[1];
    const float* alpha_bars  = (const float*)d_in[2];
    const int*   timesteps   = (const int*)d_in[3];
    float* out = (float*)d_out;

    dim3 block(256);
    dim3 grid(NBLK);
    hipLaunchKernelGGL(DiffusionScheduler_kernel, grid, block, 0, stream,
                       twist, noise, alpha_bars, timesteps, out);
}